// Round 10
// baseline (71.727 us; speedup 1.0000x reference)
//
#include <hip/hip_runtime.h>

static constexpr int NSIDE = 48;
static constexpr int NVOX  = NSIDE * NSIDE * NSIDE;   // 110592
static constexpr float SCALE = 0.041875863808787856f; // ONE_OVER_DIFF_TOT * DIFF_Q
static constexpr int NDIR  = 13;                      // canonical half of the 26 offsets
static constexpr int PAIRS_PER_BLOCK = 128;           // 4 waves x 32 pairs
static constexpr int BLOCKS_PER_DIR  = NVOX / PAIRS_PER_BLOCK;  // 864

typedef _Float16 f16x2 __attribute__((ext_vector_type(2)));
typedef _Float16 f16x8 __attribute__((ext_vector_type(8)));
typedef float    f32x16 __attribute__((ext_vector_type(16)));

union F16Frag { f16x2 h[4]; f16x8 v; };

// __builtin_amdgcn_cvt_pkrtz returns __fp16x2; bit-cast to our f16x2.
__device__ __forceinline__ f16x2 cvt_pkrtz(float a, float b) {
    return __builtin_bit_cast(f16x2, __builtin_amdgcn_cvt_pkrtz(a, b));
}

// Canonical directions (first nonzero component positive).
__device__ __constant__ int g_ox[NDIR] = { 1, 0, 0,  1, 1, 1, 1, 0, 0,  1, 1, 1, 1 };
__device__ __constant__ int g_oy[NDIR] = { 0, 1, 0,  1,-1, 0, 0, 1, 1,  1, 1,-1,-1 };
__device__ __constant__ int g_oz[NDIR] = { 0, 0, 1,  0, 0, 1,-1, 1,-1,  1,-1, 1,-1 };
__device__ __constant__ float g_dinv[NDIR] = {
    1.f, 1.f, 1.f,
    0.70710678118654752f, 0.70710678118654752f, 0.70710678118654752f,
    0.70710678118654752f, 0.70710678118654752f, 0.70710678118654752f,
    0.57735026918962576f, 0.57735026918962576f, 0.57735026918962576f, 0.57735026918962576f };

// Full 26-neighbor tables for the fallback single-pass kernel.
__device__ __constant__ int c_ox[26] = { 1,-1, 0, 0, 0, 0,
                                         1,-1, 1,-1, 1,-1, 1,-1, 0, 0, 0, 0,
                                         1, 1, 1, 1,-1,-1,-1,-1 };
__device__ __constant__ int c_oy[26] = { 0, 0, 1,-1, 0, 0,
                                         1, 1,-1,-1, 0, 0, 0, 0, 1,-1, 1,-1,
                                         1, 1,-1,-1, 1, 1,-1,-1 };
__device__ __constant__ int c_oz[26] = { 0, 0, 0, 0, 1,-1,
                                         0, 0, 0, 0, 1, 1,-1,-1, 1, 1,-1,-1,
                                         1,-1, 1,-1, 1,-1, 1,-1 };
__device__ __constant__ float c_dinv[26] = {
    1.f, 1.f, 1.f, 1.f, 1.f, 1.f,
    0.70710678118654752f, 0.70710678118654752f, 0.70710678118654752f, 0.70710678118654752f,
    0.70710678118654752f, 0.70710678118654752f, 0.70710678118654752f, 0.70710678118654752f,
    0.70710678118654752f, 0.70710678118654752f, 0.70710678118654752f, 0.70710678118654752f,
    0.57735026918962576f, 0.57735026918962576f, 0.57735026918962576f, 0.57735026918962576f,
    0.57735026918962576f, 0.57735026918962576f, 0.57735026918962576f, 0.57735026918962576f };

__device__ __forceinline__ float fast_tanh(float x) {
    // tanh(x) = 1 - 2/(exp2(2*log2e*x)+1); exact saturation at +-inf.
    float e = __builtin_amdgcn_exp2f(x * 2.8853900817779268f);
    float r = __builtin_amdgcn_rcpf(e + 1.0f);
    return fmaf(-2.0f, r, 1.0f);
}

// Packed-f16 Pade[5/4] tanh on a feature duo (xa, xb), ONE f32 rcp shared:
//   tanh x ~ x(x^4+105x^2+945)/(15x^4+420x^2+945)
// Polynomials run on v_pk_*_f16 (2 tanh per instr); result IS the next
// MFMA B-fragment half2. No clamp: pre-activations are bounded |x|<=4.25
// (|W|<=0.25, 16 inputs of |t|<=1), where raw overshoot is <=3.5e-3.
__device__ __forceinline__ f16x2 pade_act_duo(float xa, float xb) {
    const f16x2 c105 = { (_Float16)105.0f, (_Float16)105.0f };
    const f16x2 c945 = { (_Float16)945.0f, (_Float16)945.0f };
    const f16x2 c15  = { (_Float16)15.0f,  (_Float16)15.0f  };
    const f16x2 c420 = { (_Float16)420.0f, (_Float16)420.0f };
    f16x2 x   = cvt_pkrtz(xa, xb);
    f16x2 u   = x * x;
    f16x2 num = u * (u + c105) + c945;
    f16x2 den = u * (u * c15 + c420) + c945;
    const float ea = (float)den[0], eb = (float)den[1];
    const float R  = __builtin_amdgcn_rcpf(ea * eb);   // 1 trans / 2 tanh
    f16x2 s   = cvt_pkrtz(eb * R, ea * R);
    return (x * num) * s;
}

// LDS weight layout (floats):
//  W0:[0,64) b0:[64,80) W1:[80,336) b1:[336,352) W2:[352,608) b2:[608,624)
//  W3:[624,880) b3:[880,896) Wout:[896,912) bout:[912]
#define STAGE_WEIGHTS_256()                                                    \
    __shared__ __align__(16) float sw[916];                                    \
    {                                                                          \
        const int t_ = threadIdx.x;                                            \
        if (t_ <  64) sw[      t_] = W0[t_];                                   \
        if (t_ <  16) sw[ 64 + t_] = b0[t_];                                   \
                      sw[ 80 + t_] = W1[t_];                                   \
        if (t_ <  16) sw[336 + t_] = b1[t_];                                   \
                      sw[352 + t_] = W2[t_];                                   \
        if (t_ <  16) sw[608 + t_] = b2[t_];                                   \
                      sw[624 + t_] = W3[t_];                                   \
        if (t_ <  16) sw[880 + t_] = b3[t_];                                   \
        if (t_ <  16) sw[896 + t_] = Wout[t_];                                 \
        if (t_ ==  0) sw[912]     = bout[0];                                   \
        __syncthreads();                                                       \
    }

// sigma(g,p): k-index owned by lane-group g, fragment slot p. Same convention
// builds A (weights), C (biases) and B (inputs); D-chaining reproduces it, so
// any mismatch vs the HW's internal order cancels (verified on HW in R5).
// Consecutive p within each half are consecutive k -> (p,p+1) pairing is safe.
#define SIG(G, P) (((P) < 4) ? 4 * (G) + (P) : 8 + 4 * (G) + ((P) - 4))

// ---------------------------------------------------------------------------
// MFMA flux kernel: R5 chassis (1 direction per block, max TLP) + packed-f16
// Pade activations. Each wave: 32 pairs = 64 MLP instances. Hidden layers on
// v_mfma_f32_32x32x16_f16, biases ride in the C operand, f32 accumulation.
// D reg p of lane l holds feature SIG(l>>5,p) of instance l&31 -- exactly the
// B-fragment slot for the next layer: chain with zero cross-lane movement.
__global__ __launch_bounds__(256)
void flux_mfma_kernel(const float* __restrict__ q,
                      const float* __restrict__ W0, const float* __restrict__ b0,
                      const float* __restrict__ W1, const float* __restrict__ b1,
                      const float* __restrict__ W2, const float* __restrict__ b2,
                      const float* __restrict__ W3, const float* __restrict__ b3,
                      const float* __restrict__ Wout, const float* __restrict__ bout,
                      float* __restrict__ ws)
{
    STAGE_WEIGHTS_256()

    const int k    = blockIdx.x / BLOCKS_PER_DIR;                // 0..12
    const int rem  = blockIdx.x - k * BLOCKS_PER_DIR;
    const int lane = threadIdx.x & 63;
    const int wv   = threadIdx.x >> 6;
    const int g    = lane >> 5;                                  // feature-half 0/1
    const int vox  = rem * PAIRS_PER_BLOCK + wv * 32 + (lane & 31);

    const int z = vox % NSIDE;
    const int y = (vox / NSIDE) % NSIDE;
    const int x = vox / (NSIDE * NSIDE);
    const int ox = g_ox[k], oy = g_oy[k], oz = g_oz[k];
    const int nx = (ox > 0) ? ((x == NSIDE - 1) ? 0 : x + 1) : x;   // ox in {0,1}
    const int ny = (oy > 0) ? ((y == NSIDE - 1) ? 0 : y + 1)
                            : ((oy < 0) ? ((y == 0) ? NSIDE - 1 : y - 1) : y);
    const int nz = (oz > 0) ? ((z == NSIDE - 1) ? 0 : z + 1)
                            : ((oz < 0) ? ((z == 0) ? NSIDE - 1 : z - 1) : z);

    const float2 own = reinterpret_cast<const float2*>(q)[vox];
    const float2 nbq = reinterpret_cast<const float2*>(q)[(nx * NSIDE + ny) * NSIDE + nz];
    const float o0 = own.x, o1 = own.y;
    const float n0 = nbq.x, n1 = nbq.y;

    // --- fragments: hidden-layer weights (A) and biases (C) ---
    const int row = lane & 31;        // A rows >=16 feed only D regs p>=8 (never read)
    const int wr  = (row & 15) * 16;
    f16x8 aw1, aw2, aw3;
    f32x16 c1, c2, c3;
    #pragma unroll
    for (int p = 0; p < 8; ++p) {
        const int kk = SIG(g, p);
        aw1[p] = (_Float16)sw[ 80 + wr + kk];
        aw2[p] = (_Float16)sw[352 + wr + kk];
        aw3[p] = (_Float16)sw[624 + wr + kk];
        c1[p] = sw[336 + kk];
        c2[p] = sw[608 + kk];
        c3[p] = sw[880 + kk];
    }
    #pragma unroll
    for (int p = 8; p < 16; ++p) { c1[p] = 0.0f; c2[p] = 0.0f; c3[p] = 0.0f; }
    float woutv[8];
    #pragma unroll
    for (int p = 0; p < 8; ++p) woutv[p] = sw[896 + SIG(g, p)];

    // --- layer 0 (4 -> 16) dot4 on f32 VALU, activation packed per duo ---
    F16Frag ba, bb;
    #pragma unroll
    for (int p = 0; p < 8; p += 2) {
        const int f0 = SIG(g, p), f1 = SIG(g, p + 1);
        const float4 w0v = *reinterpret_cast<const float4*>(&sw[f0 * 4]);
        const float4 w1v = *reinterpret_cast<const float4*>(&sw[f1 * 4]);
        const float bb0 = sw[64 + f0], bb1 = sw[64 + f1];
        float pa0 = fmaf(w0v.x, o0, fmaf(w0v.y, o1, fmaf(w0v.z, n0, fmaf(w0v.w, n1, bb0))));
        float pa1 = fmaf(w1v.x, o0, fmaf(w1v.y, o1, fmaf(w1v.z, n0, fmaf(w1v.w, n1, bb1))));
        float pb0 = fmaf(w0v.x, n0, fmaf(w0v.y, n1, fmaf(w0v.z, o0, fmaf(w0v.w, o1, bb0))));
        float pb1 = fmaf(w1v.x, n0, fmaf(w1v.y, n1, fmaf(w1v.z, o0, fmaf(w1v.w, o1, bb1))));
        ba.h[p >> 1] = pade_act_duo(pa0, pa1);
        bb.h[p >> 1] = pade_act_duo(pb0, pb1);
    }

    // --- hidden layers 1..3 on MFMA, biases in C; packed Pade between ---
    f32x16 da, db;
    da = __builtin_amdgcn_mfma_f32_32x32x16_f16(aw1, ba.v, c1, 0, 0, 0);
    db = __builtin_amdgcn_mfma_f32_32x32x16_f16(aw1, bb.v, c1, 0, 0, 0);
    #pragma unroll
    for (int p = 0; p < 8; p += 2) {
        ba.h[p >> 1] = pade_act_duo(da[p], da[p + 1]);
        bb.h[p >> 1] = pade_act_duo(db[p], db[p + 1]);
    }
    da = __builtin_amdgcn_mfma_f32_32x32x16_f16(aw2, ba.v, c2, 0, 0, 0);
    db = __builtin_amdgcn_mfma_f32_32x32x16_f16(aw2, bb.v, c2, 0, 0, 0);
    #pragma unroll
    for (int p = 0; p < 8; p += 2) {
        ba.h[p >> 1] = pade_act_duo(da[p], da[p + 1]);
        bb.h[p >> 1] = pade_act_duo(db[p], db[p + 1]);
    }
    da = __builtin_amdgcn_mfma_f32_32x32x16_f16(aw3, ba.v, c3, 0, 0, 0);
    db = __builtin_amdgcn_mfma_f32_32x32x16_f16(aw3, bb.v, c3, 0, 0, 0);

    // --- output head (16 -> 1): packed Pade tanh, dot in f32 for accuracy;
    //     complement from lane^32. bout cancels in (oa - ob).
    float pa = 0.0f, pb = 0.0f;
    #pragma unroll
    for (int p = 0; p < 8; p += 2) {
        const f16x2 ta = pade_act_duo(da[p], da[p + 1]);
        const f16x2 tb = pade_act_duo(db[p], db[p + 1]);
        pa = fmaf((float)ta[0], woutv[p], fmaf((float)ta[1], woutv[p + 1], pa));
        pb = fmaf((float)tb[0], woutv[p], fmaf((float)tb[1], woutv[p + 1], pb));
    }
    pa += __shfl_xor(pa, 32);
    pb += __shfl_xor(pb, 32);

    const float tr  = fast_tanh(pa - pb);   // exact tanh for the final output
    const float fac = (tr < 0.0f) ? o0 : n0;
    if (lane < 32)
        ws[k * NVOX + vox] = tr * fac * g_dinv[k];
}

// ---------------------------------------------------------------------------
// Pass 2: per voxel u, total = sum_k ( f[k][u] - f[k][u - d_k] ).
__global__ __launch_bounds__(256)
void gather_kernel(const float* __restrict__ q,
                   const float* __restrict__ ws,
                   float* __restrict__ out)
{
    const int vox = blockIdx.x * 256 + threadIdx.x;

    const int z = vox % NSIDE;
    const int y = (vox / NSIDE) % NSIDE;
    const int x = vox / (NSIDE * NSIDE);
    const int xm = (x == 0) ? NSIDE - 1 : x - 1;
    const int ym = (y == 0) ? NSIDE - 1 : y - 1;
    const int yp = (y == NSIDE - 1) ? 0 : y + 1;
    const int zm = (z == 0) ? NSIDE - 1 : z - 1;
    const int zp = (z == NSIDE - 1) ? 0 : z + 1;

    float s = 0.0f;
    #pragma unroll
    for (int k = 0; k < NDIR; ++k) {
        const int px = g_ox[k] ? xm : x;
        const int py = (g_oy[k] > 0) ? ym : ((g_oy[k] < 0) ? yp : y);
        const int pz = (g_oz[k] > 0) ? zm : ((g_oz[k] < 0) ? zp : z);
        s += ws[k * NVOX + vox];
        s -= ws[k * NVOX + (px * NSIDE + py) * NSIDE + pz];
    }

    const float2 own = reinterpret_cast<const float2*>(q)[vox];
    float2 r;
    r.x = fmaf(s, SCALE, own.x);
    r.y = own.y;
    reinterpret_cast<float2*>(out)[vox] = r;
}

// ---------------------------------------------------------------------------
// Fallback: Round-3 single-pass scalar kernel (used only if ws is too small).
#define LAYER(WB, INA, INB, OUTA, OUTB)                                        \
    {                                                                          \
        _Pragma("unroll")                                                      \
        for (int i = 0; i < 16; ++i) {                                         \
            float aa = sw[(WB) + 256 + i];                                     \
            float ab = aa;                                                     \
            _Pragma("unroll")                                                  \
            for (int kk = 0; kk < 4; ++kk) {                                   \
                const float4 w = *reinterpret_cast<const float4*>(             \
                    &sw[(WB) + i * 16 + kk * 4]);                              \
                aa = fmaf(w.x, INA[4 * kk + 0], aa);                           \
                aa = fmaf(w.y, INA[4 * kk + 1], aa);                           \
                aa = fmaf(w.z, INA[4 * kk + 2], aa);                           \
                aa = fmaf(w.w, INA[4 * kk + 3], aa);                           \
                ab = fmaf(w.x, INB[4 * kk + 0], ab);                           \
                ab = fmaf(w.y, INB[4 * kk + 1], ab);                           \
                ab = fmaf(w.z, INB[4 * kk + 2], ab);                           \
                ab = fmaf(w.w, INB[4 * kk + 3], ab);                           \
            }                                                                  \
            OUTA[i] = fast_tanh(aa);                                           \
            OUTB[i] = fast_tanh(ab);                                           \
        }                                                                      \
    }

__global__ __launch_bounds__(256)
void automaton_kernel(const float* __restrict__ q,
                      const float* __restrict__ W0, const float* __restrict__ b0,
                      const float* __restrict__ W1, const float* __restrict__ b1,
                      const float* __restrict__ W2, const float* __restrict__ b2,
                      const float* __restrict__ W3, const float* __restrict__ b3,
                      const float* __restrict__ Wout, const float* __restrict__ bout,
                      float* __restrict__ out)
{
    STAGE_WEIGHTS_256()

    const int gid  = blockIdx.x * 256 + threadIdx.x;
    const int vox  = gid >> 1;
    const int half = gid & 1;

    const int z = vox % NSIDE;
    const int y = (vox / NSIDE) % NSIDE;
    const int x = vox / (NSIDE * NSIDE);
    const int xm = (x == 0) ? NSIDE - 1 : x - 1;
    const int xp = (x == NSIDE - 1) ? 0 : x + 1;
    const int ym = (y == 0) ? NSIDE - 1 : y - 1;
    const int yp = (y == NSIDE - 1) ? 0 : y + 1;
    const int zm = (z == 0) ? NSIDE - 1 : z - 1;
    const int zp = (z == NSIDE - 1) ? 0 : z + 1;

    const float2 own = reinterpret_cast<const float2*>(q)[vox];
    const float o0 = own.x, o1 = own.y;

    float sum = 0.0f;
    #pragma unroll 1
    for (int k = half * 13; k < half * 13 + 13; ++k) {
        asm volatile("" ::: "memory");   // block cross-iteration LICM of weight loads
        const int ox = c_ox[k], oy = c_oy[k], oz = c_oz[k];
        const int nx = (ox < 0) ? xm : ((ox > 0) ? xp : x);
        const int ny = (oy < 0) ? ym : ((oy > 0) ? yp : y);
        const int nz = (oz < 0) ? zm : ((oz > 0) ? zp : z);
        const float2 nbq = reinterpret_cast<const float2*>(q)[(nx * NSIDE + ny) * NSIDE + nz];
        const float n0 = nbq.x, n1 = nbq.y;

        float ha[16], hb[16], ta[16], tb[16];
        #pragma unroll
        for (int i = 0; i < 16; ++i) {
            const float4 w = *reinterpret_cast<const float4*>(&sw[i * 4]);
            const float bbias = sw[64 + i];
            float pa = fmaf(w.x, o0, fmaf(w.y, o1, fmaf(w.z, n0, fmaf(w.w, n1, bbias))));
            float pb = fmaf(w.x, n0, fmaf(w.y, n1, fmaf(w.z, o0, fmaf(w.w, o1, bbias))));
            ha[i] = fast_tanh(pa);
            hb[i] = fast_tanh(pb);
        }
        LAYER(80,  ha, hb, ta, tb)
        LAYER(352, ta, tb, ha, hb)
        LAYER(624, ha, hb, ta, tb)
        float oa = sw[912], ob = sw[912];
        #pragma unroll
        for (int kk = 0; kk < 4; ++kk) {
            const float4 w = *reinterpret_cast<const float4*>(&sw[896 + kk * 4]);
            oa = fmaf(w.x, ta[4 * kk + 0], oa);
            oa = fmaf(w.y, ta[4 * kk + 1], oa);
            oa = fmaf(w.z, ta[4 * kk + 2], oa);
            oa = fmaf(w.w, ta[4 * kk + 3], oa);
            ob = fmaf(w.x, tb[4 * kk + 0], ob);
            ob = fmaf(w.y, tb[4 * kk + 1], ob);
            ob = fmaf(w.z, tb[4 * kk + 2], ob);
            ob = fmaf(w.w, tb[4 * kk + 3], ob);
        }
        const float tr  = fast_tanh(oa - ob);
        const float fac = (tr < 0.0f) ? o0 : n0;
        sum = fmaf(tr * fac, c_dinv[k], sum);
    }

    sum += __shfl_xor(sum, 1);
    if (half == 0) {
        float2 r;
        r.x = fmaf(sum, SCALE, o0);
        r.y = o1;
        reinterpret_cast<float2*>(out)[vox] = r;
    }
}

extern "C" void kernel_launch(void* const* d_in, const int* in_sizes, int n_in,
                              void* d_out, int out_size, void* d_ws, size_t ws_size,
                              hipStream_t stream) {
    const float* q    = (const float*)d_in[0];
    const float* W0   = (const float*)d_in[1];
    const float* b0   = (const float*)d_in[2];
    const float* W1   = (const float*)d_in[3];
    const float* b1   = (const float*)d_in[4];
    const float* W2   = (const float*)d_in[5];
    const float* b2   = (const float*)d_in[6];
    const float* W3   = (const float*)d_in[7];
    const float* b3   = (const float*)d_in[8];
    const float* Wout = (const float*)d_in[9];
    const float* bout = (const float*)d_in[10];
    float* out = (float*)d_out;

    const size_t ws_needed = (size_t)NDIR * NVOX * sizeof(float);  // 5.75 MB
    if (ws_size >= ws_needed) {
        float* ws = (float*)d_ws;
        flux_mfma_kernel<<<dim3(NDIR * BLOCKS_PER_DIR), dim3(256), 0, stream>>>(
            q, W0, b0, W1, b1, W2, b2, W3, b3, Wout, bout, ws);
        gather_kernel<<<dim3(NVOX / 256), dim3(256), 0, stream>>>(q, ws, out);
    } else {
        automaton_kernel<<<dim3(NVOX * 2 / 256), dim3(256), 0, stream>>>(
            q, W0, b0, W1, b1, W2, b2, W3, b3, Wout, bout, out);
    }
}

// Round 11
// 63.036 us; speedup vs baseline: 1.1379x; 1.1379x over previous
//
#include <hip/hip_runtime.h>

static constexpr int NSIDE = 48;
static constexpr int NVOX  = NSIDE * NSIDE * NSIDE;   // 110592
static constexpr float SCALE = 0.041875863808787856f; // ONE_OVER_DIFF_TOT * DIFF_Q
static constexpr float ASCL = 2.8853900817779268f;    // 2*log2(e): tanh arg scale
static constexpr int NDIR  = 13;                      // canonical half of the 26 offsets
static constexpr int PAIRS_PER_BLOCK = 128;           // 4 waves x 32 pairs
static constexpr int BLOCKS_PER_DIR  = NVOX / PAIRS_PER_BLOCK;  // 864

typedef _Float16 f16x2 __attribute__((ext_vector_type(2)));
typedef _Float16 f16x8 __attribute__((ext_vector_type(8)));
typedef float    f32x16 __attribute__((ext_vector_type(16)));

union F16Frag { f16x2 h[4]; f16x8 v; };

// __builtin_amdgcn_cvt_pkrtz returns __fp16x2; bit-cast to our f16x2.
__device__ __forceinline__ f16x2 cvt_pkrtz(float a, float b) {
    return __builtin_bit_cast(f16x2, __builtin_amdgcn_cvt_pkrtz(a, b));
}

// Canonical directions (first nonzero component positive).
__device__ __constant__ int g_ox[NDIR] = { 1, 0, 0,  1, 1, 1, 1, 0, 0,  1, 1, 1, 1 };
__device__ __constant__ int g_oy[NDIR] = { 0, 1, 0,  1,-1, 0, 0, 1, 1,  1, 1,-1,-1 };
__device__ __constant__ int g_oz[NDIR] = { 0, 0, 1,  0, 0, 1,-1, 1,-1,  1,-1, 1,-1 };
__device__ __constant__ float g_dinv[NDIR] = {
    1.f, 1.f, 1.f,
    0.70710678118654752f, 0.70710678118654752f, 0.70710678118654752f,
    0.70710678118654752f, 0.70710678118654752f, 0.70710678118654752f,
    0.57735026918962576f, 0.57735026918962576f, 0.57735026918962576f, 0.57735026918962576f };

// Full 26-neighbor tables for the fallback single-pass kernel.
__device__ __constant__ int c_ox[26] = { 1,-1, 0, 0, 0, 0,
                                         1,-1, 1,-1, 1,-1, 1,-1, 0, 0, 0, 0,
                                         1, 1, 1, 1,-1,-1,-1,-1 };
__device__ __constant__ int c_oy[26] = { 0, 0, 1,-1, 0, 0,
                                         1, 1,-1,-1, 0, 0, 0, 0, 1,-1, 1,-1,
                                         1, 1,-1,-1, 1, 1,-1,-1 };
__device__ __constant__ int c_oz[26] = { 0, 0, 0, 0, 1,-1,
                                         0, 0, 0, 0, 1, 1,-1,-1, 1, 1,-1,-1,
                                         1,-1, 1,-1, 1,-1, 1,-1 };
__device__ __constant__ float c_dinv[26] = {
    1.f, 1.f, 1.f, 1.f, 1.f, 1.f,
    0.70710678118654752f, 0.70710678118654752f, 0.70710678118654752f, 0.70710678118654752f,
    0.70710678118654752f, 0.70710678118654752f, 0.70710678118654752f, 0.70710678118654752f,
    0.70710678118654752f, 0.70710678118654752f, 0.70710678118654752f, 0.70710678118654752f,
    0.57735026918962576f, 0.57735026918962576f, 0.57735026918962576f, 0.57735026918962576f,
    0.57735026918962576f, 0.57735026918962576f, 0.57735026918962576f, 0.57735026918962576f };

__device__ __forceinline__ float fast_tanh(float x) {
    // tanh(x) = 1 - 2/(exp2(2*log2e*x)+1); exact saturation at +-inf.
    float e = __builtin_amdgcn_exp2f(x * ASCL);
    float r = __builtin_amdgcn_rcpf(e + 1.0f);
    return fmaf(-2.0f, r, 1.0f);
}

// tanh for PRE-SCALED argument y = ASCL*x (scale folded into the weights):
// no v_mul -- 2 VALU + 2 trans. Trans pipe runs parallel to VALU (R10 lesson).
__device__ __forceinline__ float fast_tanh_pre(float y) {
    float e = __builtin_amdgcn_exp2f(y);
    float r = __builtin_amdgcn_rcpf(e + 1.0f);
    return fmaf(-2.0f, r, 1.0f);
}

// LDS weight layout (floats):
//  W0:[0,64) b0:[64,80) W1:[80,336) b1:[336,352) W2:[352,608) b2:[608,624)
//  W3:[624,880) b3:[880,896) Wout:[896,912) bout:[912]
// Flux version stages ALL weights/biases pre-scaled by ASCL so every tanh
// argument arrives already multiplied (tanh outputs are unchanged, so
// layer chaining is exact; bout cancels in the antisymmetric difference).
#define STAGE_WEIGHTS_SCALED_256()                                             \
    __shared__ __align__(16) float sw[916];                                    \
    {                                                                          \
        const int t_ = threadIdx.x;                                            \
        if (t_ <  64) sw[      t_] = W0[t_] * ASCL;                            \
        if (t_ <  16) sw[ 64 + t_] = b0[t_] * ASCL;                            \
                      sw[ 80 + t_] = W1[t_] * ASCL;                            \
        if (t_ <  16) sw[336 + t_] = b1[t_] * ASCL;                            \
                      sw[352 + t_] = W2[t_] * ASCL;                            \
        if (t_ <  16) sw[608 + t_] = b2[t_] * ASCL;                            \
                      sw[624 + t_] = W3[t_] * ASCL;                            \
        if (t_ <  16) sw[880 + t_] = b3[t_] * ASCL;                            \
        if (t_ <  16) sw[896 + t_] = Wout[t_] * ASCL;                          \
        if (t_ ==  0) sw[912]     = bout[0];                                   \
        __syncthreads();                                                       \
    }

#define STAGE_WEIGHTS_256()                                                    \
    __shared__ __align__(16) float sw[916];                                    \
    {                                                                          \
        const int t_ = threadIdx.x;                                            \
        if (t_ <  64) sw[      t_] = W0[t_];                                   \
        if (t_ <  16) sw[ 64 + t_] = b0[t_];                                   \
                      sw[ 80 + t_] = W1[t_];                                   \
        if (t_ <  16) sw[336 + t_] = b1[t_];                                   \
                      sw[352 + t_] = W2[t_];                                   \
        if (t_ <  16) sw[608 + t_] = b2[t_];                                   \
                      sw[624 + t_] = W3[t_];                                   \
        if (t_ <  16) sw[880 + t_] = b3[t_];                                   \
        if (t_ <  16) sw[896 + t_] = Wout[t_];                                 \
        if (t_ ==  0) sw[912]     = bout[0];                                   \
    __syncthreads();                                                           \
    }

// sigma(g,p): k-index owned by lane-group g, fragment slot p. Same convention
// builds A (weights), C (biases) and B (inputs); D-chaining reproduces it, so
// any mismatch vs the HW's internal order cancels (verified on HW in R5).
// Consecutive p within each half are consecutive k -> (p,p+1) pairing is safe.
#define SIG(G, P) (((P) < 4) ? 4 * (G) + (P) : 8 + 4 * (G) + ((P) - 4))

// ---------------------------------------------------------------------------
// MFMA flux kernel: R5 chassis (1 direction per block, max TLP; best measured)
// + two VALU cuts: (1) ASCL folded into weights (tanh loses its v_mul),
// (2) cvt_pkrtz duo packing (replaces per-elem cvt+pack). tanh itself stays
// on the parallel trans pipe (~55% busy) via exp2+rcp.
__global__ __launch_bounds__(256)
void flux_mfma_kernel(const float* __restrict__ q,
                      const float* __restrict__ W0, const float* __restrict__ b0,
                      const float* __restrict__ W1, const float* __restrict__ b1,
                      const float* __restrict__ W2, const float* __restrict__ b2,
                      const float* __restrict__ W3, const float* __restrict__ b3,
                      const float* __restrict__ Wout, const float* __restrict__ bout,
                      float* __restrict__ ws)
{
    STAGE_WEIGHTS_SCALED_256()

    const int k    = blockIdx.x / BLOCKS_PER_DIR;                // 0..12
    const int rem  = blockIdx.x - k * BLOCKS_PER_DIR;
    const int lane = threadIdx.x & 63;
    const int wv   = threadIdx.x >> 6;
    const int g    = lane >> 5;                                  // feature-half 0/1
    const int vox  = rem * PAIRS_PER_BLOCK + wv * 32 + (lane & 31);

    const int z = vox % NSIDE;
    const int y = (vox / NSIDE) % NSIDE;
    const int x = vox / (NSIDE * NSIDE);
    const int ox = g_ox[k], oy = g_oy[k], oz = g_oz[k];
    const int nx = (ox > 0) ? ((x == NSIDE - 1) ? 0 : x + 1) : x;   // ox in {0,1}
    const int ny = (oy > 0) ? ((y == NSIDE - 1) ? 0 : y + 1)
                            : ((oy < 0) ? ((y == 0) ? NSIDE - 1 : y - 1) : y);
    const int nz = (oz > 0) ? ((z == NSIDE - 1) ? 0 : z + 1)
                            : ((oz < 0) ? ((z == 0) ? NSIDE - 1 : z - 1) : z);

    const float2 own = reinterpret_cast<const float2*>(q)[vox];
    const float2 nbq = reinterpret_cast<const float2*>(q)[(nx * NSIDE + ny) * NSIDE + nz];
    const float o0 = own.x, o1 = own.y;
    const float n0 = nbq.x, n1 = nbq.y;

    // --- fragments: scaled hidden-layer weights (A) and scaled biases (C) ---
    const int row = lane & 31;        // A rows >=16 feed only D regs p>=8 (never read)
    const int wr  = (row & 15) * 16;
    f16x8 aw1, aw2, aw3;
    f32x16 c1, c2, c3;
    #pragma unroll
    for (int p = 0; p < 8; ++p) {
        const int kk = SIG(g, p);
        aw1[p] = (_Float16)sw[ 80 + wr + kk];
        aw2[p] = (_Float16)sw[352 + wr + kk];
        aw3[p] = (_Float16)sw[624 + wr + kk];
        c1[p] = sw[336 + kk];
        c2[p] = sw[608 + kk];
        c3[p] = sw[880 + kk];
    }
    #pragma unroll
    for (int p = 8; p < 16; ++p) { c1[p] = 0.0f; c2[p] = 0.0f; c3[p] = 0.0f; }
    float woutv[8];
    #pragma unroll
    for (int p = 0; p < 8; ++p) woutv[p] = sw[896 + SIG(g, p)];

    // --- layer 0 (4 -> 16): scaled dot4, mul-free tanh, pkrtz-packed ---
    F16Frag ba, bb;
    #pragma unroll
    for (int p = 0; p < 8; p += 2) {
        const int f0 = SIG(g, p), f1 = SIG(g, p + 1);
        const float4 w0v = *reinterpret_cast<const float4*>(&sw[f0 * 4]);
        const float4 w1v = *reinterpret_cast<const float4*>(&sw[f1 * 4]);
        const float bb0 = sw[64 + f0], bb1 = sw[64 + f1];
        float pa0 = fmaf(w0v.x, o0, fmaf(w0v.y, o1, fmaf(w0v.z, n0, fmaf(w0v.w, n1, bb0))));
        float pa1 = fmaf(w1v.x, o0, fmaf(w1v.y, o1, fmaf(w1v.z, n0, fmaf(w1v.w, n1, bb1))));
        float pb0 = fmaf(w0v.x, n0, fmaf(w0v.y, n1, fmaf(w0v.z, o0, fmaf(w0v.w, o1, bb0))));
        float pb1 = fmaf(w1v.x, n0, fmaf(w1v.y, n1, fmaf(w1v.z, o0, fmaf(w1v.w, o1, bb1))));
        ba.h[p >> 1] = cvt_pkrtz(fast_tanh_pre(pa0), fast_tanh_pre(pa1));
        bb.h[p >> 1] = cvt_pkrtz(fast_tanh_pre(pb0), fast_tanh_pre(pb1));
    }

    // --- hidden layers 1..3 on MFMA (scaled A & C -> pre-scaled args) ---
    f32x16 da, db;
    da = __builtin_amdgcn_mfma_f32_32x32x16_f16(aw1, ba.v, c1, 0, 0, 0);
    db = __builtin_amdgcn_mfma_f32_32x32x16_f16(aw1, bb.v, c1, 0, 0, 0);
    #pragma unroll
    for (int p = 0; p < 8; p += 2) {
        ba.h[p >> 1] = cvt_pkrtz(fast_tanh_pre(da[p]), fast_tanh_pre(da[p + 1]));
        bb.h[p >> 1] = cvt_pkrtz(fast_tanh_pre(db[p]), fast_tanh_pre(db[p + 1]));
    }
    da = __builtin_amdgcn_mfma_f32_32x32x16_f16(aw2, ba.v, c2, 0, 0, 0);
    db = __builtin_amdgcn_mfma_f32_32x32x16_f16(aw2, bb.v, c2, 0, 0, 0);
    #pragma unroll
    for (int p = 0; p < 8; p += 2) {
        ba.h[p >> 1] = cvt_pkrtz(fast_tanh_pre(da[p]), fast_tanh_pre(da[p + 1]));
        bb.h[p >> 1] = cvt_pkrtz(fast_tanh_pre(db[p]), fast_tanh_pre(db[p + 1]));
    }
    da = __builtin_amdgcn_mfma_f32_32x32x16_f16(aw3, ba.v, c3, 0, 0, 0);
    db = __builtin_amdgcn_mfma_f32_32x32x16_f16(aw3, bb.v, c3, 0, 0, 0);

    // --- output head (16 -> 1): tanh then f32 partial dot with SCALED wout;
    //     pa-pb is then the pre-scaled final argument. Complement from
    //     lane^32; bout cancels in the difference.
    float pa = 0.0f, pb = 0.0f;
    #pragma unroll
    for (int p = 0; p < 8; ++p) {
        pa = fmaf(fast_tanh_pre(da[p]), woutv[p], pa);
        pb = fmaf(fast_tanh_pre(db[p]), woutv[p], pb);
    }
    pa += __shfl_xor(pa, 32);
    pb += __shfl_xor(pb, 32);

    const float tr  = fast_tanh_pre(pa - pb);   // arg pre-scaled via woutv
    const float fac = (tr < 0.0f) ? o0 : n0;
    if (lane < 32)
        ws[k * NVOX + vox] = tr * fac * g_dinv[k];
}

// ---------------------------------------------------------------------------
// Pass 2: per voxel u, total = sum_k ( f[k][u] - f[k][u - d_k] ).
__global__ __launch_bounds__(256)
void gather_kernel(const float* __restrict__ q,
                   const float* __restrict__ ws,
                   float* __restrict__ out)
{
    const int vox = blockIdx.x * 256 + threadIdx.x;

    const int z = vox % NSIDE;
    const int y = (vox / NSIDE) % NSIDE;
    const int x = vox / (NSIDE * NSIDE);
    const int xm = (x == 0) ? NSIDE - 1 : x - 1;
    const int ym = (y == 0) ? NSIDE - 1 : y - 1;
    const int yp = (y == NSIDE - 1) ? 0 : y + 1;
    const int zm = (z == 0) ? NSIDE - 1 : z - 1;
    const int zp = (z == NSIDE - 1) ? 0 : z + 1;

    float s = 0.0f;
    #pragma unroll
    for (int k = 0; k < NDIR; ++k) {
        const int px = g_ox[k] ? xm : x;
        const int py = (g_oy[k] > 0) ? ym : ((g_oy[k] < 0) ? yp : y);
        const int pz = (g_oz[k] > 0) ? zm : ((g_oz[k] < 0) ? zp : z);
        s += ws[k * NVOX + vox];
        s -= ws[k * NVOX + (px * NSIDE + py) * NSIDE + pz];
    }

    const float2 own = reinterpret_cast<const float2*>(q)[vox];
    float2 r;
    r.x = fmaf(s, SCALE, own.x);
    r.y = own.y;
    reinterpret_cast<float2*>(out)[vox] = r;
}

// ---------------------------------------------------------------------------
// Fallback: Round-3 single-pass scalar kernel (used only if ws is too small).
#define LAYER(WB, INA, INB, OUTA, OUTB)                                        \
    {                                                                          \
        _Pragma("unroll")                                                      \
        for (int i = 0; i < 16; ++i) {                                         \
            float aa = sw[(WB) + 256 + i];                                     \
            float ab = aa;                                                     \
            _Pragma("unroll")                                                  \
            for (int kk = 0; kk < 4; ++kk) {                                   \
                const float4 w = *reinterpret_cast<const float4*>(             \
                    &sw[(WB) + i * 16 + kk * 4]);                              \
                aa = fmaf(w.x, INA[4 * kk + 0], aa);                           \
                aa = fmaf(w.y, INA[4 * kk + 1], aa);                           \
                aa = fmaf(w.z, INA[4 * kk + 2], aa);                           \
                aa = fmaf(w.w, INA[4 * kk + 3], aa);                           \
                ab = fmaf(w.x, INB[4 * kk + 0], ab);                           \
                ab = fmaf(w.y, INB[4 * kk + 1], ab);                           \
                ab = fmaf(w.z, INB[4 * kk + 2], ab);                           \
                ab = fmaf(w.w, INB[4 * kk + 3], ab);                           \
            }                                                                  \
            OUTA[i] = fast_tanh(aa);                                           \
            OUTB[i] = fast_tanh(ab);                                           \
        }                                                                      \
    }

__global__ __launch_bounds__(256)
void automaton_kernel(const float* __restrict__ q,
                      const float* __restrict__ W0, const float* __restrict__ b0,
                      const float* __restrict__ W1, const float* __restrict__ b1,
                      const float* __restrict__ W2, const float* __restrict__ b2,
                      const float* __restrict__ W3, const float* __restrict__ b3,
                      const float* __restrict__ Wout, const float* __restrict__ bout,
                      float* __restrict__ out)
{
    STAGE_WEIGHTS_256()

    const int gid  = blockIdx.x * 256 + threadIdx.x;
    const int vox  = gid >> 1;
    const int half = gid & 1;

    const int z = vox % NSIDE;
    const int y = (vox / NSIDE) % NSIDE;
    const int x = vox / (NSIDE * NSIDE);
    const int xm = (x == 0) ? NSIDE - 1 : x - 1;
    const int xp = (x == NSIDE - 1) ? 0 : x + 1;
    const int ym = (y == 0) ? NSIDE - 1 : y - 1;
    const int yp = (y == NSIDE - 1) ? 0 : y + 1;
    const int zm = (z == 0) ? NSIDE - 1 : z - 1;
    const int zp = (z == NSIDE - 1) ? 0 : z + 1;

    const float2 own = reinterpret_cast<const float2*>(q)[vox];
    const float o0 = own.x, o1 = own.y;

    float sum = 0.0f;
    #pragma unroll 1
    for (int k = half * 13; k < half * 13 + 13; ++k) {
        asm volatile("" ::: "memory");   // block cross-iteration LICM of weight loads
        const int ox = c_ox[k], oy = c_oy[k], oz = c_oz[k];
        const int nx = (ox < 0) ? xm : ((ox > 0) ? xp : x);
        const int ny = (oy < 0) ? ym : ((oy > 0) ? yp : y);
        const int nz = (oz < 0) ? zm : ((oz > 0) ? zp : z);
        const float2 nbq = reinterpret_cast<const float2*>(q)[(nx * NSIDE + ny) * NSIDE + nz];
        const float n0 = nbq.x, n1 = nbq.y;

        float ha[16], hb[16], ta[16], tb[16];
        #pragma unroll
        for (int i = 0; i < 16; ++i) {
            const float4 w = *reinterpret_cast<const float4*>(&sw[i * 4]);
            const float bbias = sw[64 + i];
            float pa = fmaf(w.x, o0, fmaf(w.y, o1, fmaf(w.z, n0, fmaf(w.w, n1, bbias))));
            float pb = fmaf(w.x, n0, fmaf(w.y, n1, fmaf(w.z, o0, fmaf(w.w, o1, bbias))));
            ha[i] = fast_tanh(pa);
            hb[i] = fast_tanh(pb);
        }
        LAYER(80,  ha, hb, ta, tb)
        LAYER(352, ta, tb, ha, hb)
        LAYER(624, ha, hb, ta, tb)
        float oa = sw[912], ob = sw[912];
        #pragma unroll
        for (int kk = 0; kk < 4; ++kk) {
            const float4 w = *reinterpret_cast<const float4*>(&sw[896 + kk * 4]);
            oa = fmaf(w.x, ta[4 * kk + 0], oa);
            oa = fmaf(w.y, ta[4 * kk + 1], oa);
            oa = fmaf(w.z, ta[4 * kk + 2], oa);
            oa = fmaf(w.w, ta[4 * kk + 3], oa);
            ob = fmaf(w.x, tb[4 * kk + 0], ob);
            ob = fmaf(w.y, tb[4 * kk + 1], ob);
            ob = fmaf(w.z, tb[4 * kk + 2], ob);
            ob = fmaf(w.w, tb[4 * kk + 3], ob);
        }
        const float tr  = fast_tanh(oa - ob);
        const float fac = (tr < 0.0f) ? o0 : n0;
        sum = fmaf(tr * fac, c_dinv[k], sum);
    }

    sum += __shfl_xor(sum, 1);
    if (half == 0) {
        float2 r;
        r.x = fmaf(sum, SCALE, o0);
        r.y = o1;
        reinterpret_cast<float2*>(out)[vox] = r;
    }
}

extern "C" void kernel_launch(void* const* d_in, const int* in_sizes, int n_in,
                              void* d_out, int out_size, void* d_ws, size_t ws_size,
                              hipStream_t stream) {
    const float* q    = (const float*)d_in[0];
    const float* W0   = (const float*)d_in[1];
    const float* b0   = (const float*)d_in[2];
    const float* W1   = (const float*)d_in[3];
    const float* b1   = (const float*)d_in[4];
    const float* W2   = (const float*)d_in[5];
    const float* b2   = (const float*)d_in[6];
    const float* W3   = (const float*)d_in[7];
    const float* b3   = (const float*)d_in[8];
    const float* Wout = (const float*)d_in[9];
    const float* bout = (const float*)d_in[10];
    float* out = (float*)d_out;

    const size_t ws_needed = (size_t)NDIR * NVOX * sizeof(float);  // 5.75 MB
    if (ws_size >= ws_needed) {
        float* ws = (float*)d_ws;
        flux_mfma_kernel<<<dim3(NDIR * BLOCKS_PER_DIR), dim3(256), 0, stream>>>(
            q, W0, b0, W1, b1, W2, b2, W3, b3, Wout, bout, ws);
        gather_kernel<<<dim3(NVOX / 256), dim3(256), 0, stream>>>(q, ws, out);
    } else {
        automaton_kernel<<<dim3(NVOX * 2 / 256), dim3(256), 0, stream>>>(
            q, W0, b0, W1, b1, W2, b2, W3, b3, Wout, bout, out);
    }
}

// Round 12
// 56.168 us; speedup vs baseline: 1.2770x; 1.1223x over previous
//
#include <hip/hip_runtime.h>

static constexpr int NSIDE = 48;
static constexpr int NVOX  = NSIDE * NSIDE * NSIDE;   // 110592
static constexpr float SCALE = 0.041875863808787856f; // ONE_OVER_DIFF_TOT * DIFF_Q
static constexpr float ASCL = 2.8853900817779268f;    // 2*log2(e): tanh arg scale
static constexpr int NDIR  = 13;                      // canonical half of the 26 offsets
static constexpr int PAIRS_PER_BLOCK = 128;           // 4 waves x 32 pairs
static constexpr int BLOCKS_PER_DIR  = NVOX / PAIRS_PER_BLOCK;  // 864

typedef _Float16 f16x2 __attribute__((ext_vector_type(2)));
typedef _Float16 f16x8 __attribute__((ext_vector_type(8)));
typedef float    f32x16 __attribute__((ext_vector_type(16)));

union F16Frag { f16x2 h[4]; f16x8 v; };

// __builtin_amdgcn_cvt_pkrtz returns __fp16x2; bit-cast to our f16x2.
__device__ __forceinline__ f16x2 cvt_pkrtz(float a, float b) {
    return __builtin_bit_cast(f16x2, __builtin_amdgcn_cvt_pkrtz(a, b));
}

// Canonical directions (first nonzero component positive).
__device__ __constant__ int g_ox[NDIR] = { 1, 0, 0,  1, 1, 1, 1, 0, 0,  1, 1, 1, 1 };
__device__ __constant__ int g_oy[NDIR] = { 0, 1, 0,  1,-1, 0, 0, 1, 1,  1, 1,-1,-1 };
__device__ __constant__ int g_oz[NDIR] = { 0, 0, 1,  0, 0, 1,-1, 1,-1,  1,-1, 1,-1 };
__device__ __constant__ float g_dinv[NDIR] = {
    1.f, 1.f, 1.f,
    0.70710678118654752f, 0.70710678118654752f, 0.70710678118654752f,
    0.70710678118654752f, 0.70710678118654752f, 0.70710678118654752f,
    0.57735026918962576f, 0.57735026918962576f, 0.57735026918962576f, 0.57735026918962576f };

// Full 26-neighbor tables for the fallback single-pass kernel.
__device__ __constant__ int c_ox[26] = { 1,-1, 0, 0, 0, 0,
                                         1,-1, 1,-1, 1,-1, 1,-1, 0, 0, 0, 0,
                                         1, 1, 1, 1,-1,-1,-1,-1 };
__device__ __constant__ int c_oy[26] = { 0, 0, 1,-1, 0, 0,
                                         1, 1,-1,-1, 0, 0, 0, 0, 1,-1, 1,-1,
                                         1, 1,-1,-1, 1, 1,-1,-1 };
__device__ __constant__ int c_oz[26] = { 0, 0, 0, 0, 1,-1,
                                         0, 0, 0, 0, 1, 1,-1,-1, 1, 1,-1,-1,
                                         1,-1, 1,-1, 1,-1, 1,-1 };
__device__ __constant__ float c_dinv[26] = {
    1.f, 1.f, 1.f, 1.f, 1.f, 1.f,
    0.70710678118654752f, 0.70710678118654752f, 0.70710678118654752f, 0.70710678118654752f,
    0.70710678118654752f, 0.70710678118654752f, 0.70710678118654752f, 0.70710678118654752f,
    0.70710678118654752f, 0.70710678118654752f, 0.70710678118654752f, 0.70710678118654752f,
    0.57735026918962576f, 0.57735026918962576f, 0.57735026918962576f, 0.57735026918962576f,
    0.57735026918962576f, 0.57735026918962576f, 0.57735026918962576f, 0.57735026918962576f };

__device__ __forceinline__ float fast_tanh(float x) {
    // tanh(x) = 1 - 2/(exp2(2*log2e*x)+1); exact saturation at +-inf.
    float e = __builtin_amdgcn_exp2f(x * ASCL);
    float r = __builtin_amdgcn_rcpf(e + 1.0f);
    return fmaf(-2.0f, r, 1.0f);
}

// tanh for PRE-SCALED argument y = ASCL*x (scale folded into the weights):
// no v_mul -- 2 VALU + 2 trans.
__device__ __forceinline__ float fast_tanh_pre(float y) {
    float e = __builtin_amdgcn_exp2f(y);
    float r = __builtin_amdgcn_rcpf(e + 1.0f);
    return fmaf(-2.0f, r, 1.0f);
}

// LDS weight layout (floats):
//  W0:[0,64) b0:[64,80) W1:[80,336) b1:[336,352) W2:[352,608) b2:[608,624)
//  W3:[624,880) b3:[880,896) Wout:[896,912) bout:[912]
// Flux version stages ALL weights/biases pre-scaled by ASCL so every tanh
// argument arrives already multiplied (tanh outputs unchanged -> chaining
// exact; bout cancels in the antisymmetric difference).
#define STAGE_WEIGHTS_SCALED_256()                                             \
    __shared__ __align__(16) float sw[916];                                    \
    {                                                                          \
        const int t_ = threadIdx.x;                                            \
        if (t_ <  64) sw[      t_] = W0[t_] * ASCL;                            \
        if (t_ <  16) sw[ 64 + t_] = b0[t_] * ASCL;                            \
                      sw[ 80 + t_] = W1[t_] * ASCL;                            \
        if (t_ <  16) sw[336 + t_] = b1[t_] * ASCL;                            \
                      sw[352 + t_] = W2[t_] * ASCL;                            \
        if (t_ <  16) sw[608 + t_] = b2[t_] * ASCL;                            \
                      sw[624 + t_] = W3[t_] * ASCL;                            \
        if (t_ <  16) sw[880 + t_] = b3[t_] * ASCL;                            \
        if (t_ <  16) sw[896 + t_] = Wout[t_] * ASCL;                          \
        if (t_ ==  0) sw[912]     = bout[0];                                   \
        __syncthreads();                                                       \
    }

#define STAGE_WEIGHTS_256()                                                    \
    __shared__ __align__(16) float sw[916];                                    \
    {                                                                          \
        const int t_ = threadIdx.x;                                            \
        if (t_ <  64) sw[      t_] = W0[t_];                                   \
        if (t_ <  16) sw[ 64 + t_] = b0[t_];                                   \
                      sw[ 80 + t_] = W1[t_];                                   \
        if (t_ <  16) sw[336 + t_] = b1[t_];                                   \
                      sw[352 + t_] = W2[t_];                                   \
        if (t_ <  16) sw[608 + t_] = b2[t_];                                   \
                      sw[624 + t_] = W3[t_];                                   \
        if (t_ <  16) sw[880 + t_] = b3[t_];                                   \
        if (t_ <  16) sw[896 + t_] = Wout[t_];                                 \
        if (t_ ==  0) sw[912]     = bout[0];                                   \
    __syncthreads();                                                           \
    }

// sigma(g,p): k-index owned by lane-group g, fragment slot p. Same convention
// builds A (weights), C (biases) and B (inputs); D-chaining reproduces it, so
// any mismatch vs the HW's internal order cancels (verified on HW in R5).
// Consecutive p within each half are consecutive k -> (p,p+1) pairing is safe.
#define SIG(G, P) (((P) < 4) ? 4 * (G) + (P) : 8 + 4 * (G) + ((P) - 4))

// ---------------------------------------------------------------------------
// MFMA flux kernel: R11 body + JUST-IN-TIME fragment loads. Compiler barriers
// between layer stages keep each layer's (aw, c) LDS reads from being hoisted
// -- only ONE layer's fragments are live at a time, cutting peak VGPR (R11's
// 68-reg / 29%-occupancy regression vs R5's 60/38.8%; this kernel is
// latency-bound, occupancy is the lever).
__global__ __launch_bounds__(256)
void flux_mfma_kernel(const float* __restrict__ q,
                      const float* __restrict__ W0, const float* __restrict__ b0,
                      const float* __restrict__ W1, const float* __restrict__ b1,
                      const float* __restrict__ W2, const float* __restrict__ b2,
                      const float* __restrict__ W3, const float* __restrict__ b3,
                      const float* __restrict__ Wout, const float* __restrict__ bout,
                      float* __restrict__ ws)
{
    STAGE_WEIGHTS_SCALED_256()

    const int k    = blockIdx.x / BLOCKS_PER_DIR;                // 0..12
    const int rem  = blockIdx.x - k * BLOCKS_PER_DIR;
    const int lane = threadIdx.x & 63;
    const int wv   = threadIdx.x >> 6;
    const int g    = lane >> 5;                                  // feature-half 0/1
    const int vox  = rem * PAIRS_PER_BLOCK + wv * 32 + (lane & 31);

    const int z = vox % NSIDE;
    const int y = (vox / NSIDE) % NSIDE;
    const int x = vox / (NSIDE * NSIDE);
    const int ox = g_ox[k], oy = g_oy[k], oz = g_oz[k];
    const int nx = (ox > 0) ? ((x == NSIDE - 1) ? 0 : x + 1) : x;   // ox in {0,1}
    const int ny = (oy > 0) ? ((y == NSIDE - 1) ? 0 : y + 1)
                            : ((oy < 0) ? ((y == 0) ? NSIDE - 1 : y - 1) : y);
    const int nz = (oz > 0) ? ((z == NSIDE - 1) ? 0 : z + 1)
                            : ((oz < 0) ? ((z == 0) ? NSIDE - 1 : z - 1) : z);

    const float2 own = reinterpret_cast<const float2*>(q)[vox];
    const float2 nbq = reinterpret_cast<const float2*>(q)[(nx * NSIDE + ny) * NSIDE + nz];
    const float o0 = own.x, o1 = own.y;
    const float n0 = nbq.x, n1 = nbq.y;

    const int row = lane & 31;        // A rows >=16 feed only D regs p>=8 (never read)
    const int wr  = (row & 15) * 16;

    // --- layer 0 (4 -> 16): scaled dot4, mul-free tanh, pkrtz-packed ---
    F16Frag ba, bb;
    #pragma unroll
    for (int p = 0; p < 8; p += 2) {
        const int f0 = SIG(g, p), f1 = SIG(g, p + 1);
        const float4 w0v = *reinterpret_cast<const float4*>(&sw[f0 * 4]);
        const float4 w1v = *reinterpret_cast<const float4*>(&sw[f1 * 4]);
        const float bb0 = sw[64 + f0], bb1 = sw[64 + f1];
        float pa0 = fmaf(w0v.x, o0, fmaf(w0v.y, o1, fmaf(w0v.z, n0, fmaf(w0v.w, n1, bb0))));
        float pa1 = fmaf(w1v.x, o0, fmaf(w1v.y, o1, fmaf(w1v.z, n0, fmaf(w1v.w, n1, bb1))));
        float pb0 = fmaf(w0v.x, n0, fmaf(w0v.y, n1, fmaf(w0v.z, o0, fmaf(w0v.w, o1, bb0))));
        float pb1 = fmaf(w1v.x, n0, fmaf(w1v.y, n1, fmaf(w1v.z, o0, fmaf(w1v.w, o1, bb1))));
        ba.h[p >> 1] = cvt_pkrtz(fast_tanh_pre(pa0), fast_tanh_pre(pa1));
        bb.h[p >> 1] = cvt_pkrtz(fast_tanh_pre(pb0), fast_tanh_pre(pb1));
    }

    f32x16 da, db;

    // --- layer 1: just-in-time fragment load, then MFMA + act ---
    asm volatile("" ::: "memory");   // fence: no hoisting of these LDS reads
    {
        f16x8 aw;
        f32x16 c;
        #pragma unroll
        for (int p = 0; p < 8; ++p) {
            const int kk = SIG(g, p);
            aw[p] = (_Float16)sw[80 + wr + kk];
            c[p]  = sw[336 + kk];
        }
        #pragma unroll
        for (int p = 8; p < 16; ++p) c[p] = 0.0f;
        da = __builtin_amdgcn_mfma_f32_32x32x16_f16(aw, ba.v, c, 0, 0, 0);
        db = __builtin_amdgcn_mfma_f32_32x32x16_f16(aw, bb.v, c, 0, 0, 0);
    }
    #pragma unroll
    for (int p = 0; p < 8; p += 2) {
        ba.h[p >> 1] = cvt_pkrtz(fast_tanh_pre(da[p]), fast_tanh_pre(da[p + 1]));
        bb.h[p >> 1] = cvt_pkrtz(fast_tanh_pre(db[p]), fast_tanh_pre(db[p + 1]));
    }

    // --- layer 2 ---
    asm volatile("" ::: "memory");
    {
        f16x8 aw;
        f32x16 c;
        #pragma unroll
        for (int p = 0; p < 8; ++p) {
            const int kk = SIG(g, p);
            aw[p] = (_Float16)sw[352 + wr + kk];
            c[p]  = sw[608 + kk];
        }
        #pragma unroll
        for (int p = 8; p < 16; ++p) c[p] = 0.0f;
        da = __builtin_amdgcn_mfma_f32_32x32x16_f16(aw, ba.v, c, 0, 0, 0);
        db = __builtin_amdgcn_mfma_f32_32x32x16_f16(aw, bb.v, c, 0, 0, 0);
    }
    #pragma unroll
    for (int p = 0; p < 8; p += 2) {
        ba.h[p >> 1] = cvt_pkrtz(fast_tanh_pre(da[p]), fast_tanh_pre(da[p + 1]));
        bb.h[p >> 1] = cvt_pkrtz(fast_tanh_pre(db[p]), fast_tanh_pre(db[p + 1]));
    }

    // --- layer 3 ---
    asm volatile("" ::: "memory");
    {
        f16x8 aw;
        f32x16 c;
        #pragma unroll
        for (int p = 0; p < 8; ++p) {
            const int kk = SIG(g, p);
            aw[p] = (_Float16)sw[624 + wr + kk];
            c[p]  = sw[880 + kk];
        }
        #pragma unroll
        for (int p = 8; p < 16; ++p) c[p] = 0.0f;
        da = __builtin_amdgcn_mfma_f32_32x32x16_f16(aw, ba.v, c, 0, 0, 0);
        db = __builtin_amdgcn_mfma_f32_32x32x16_f16(aw, bb.v, c, 0, 0, 0);
    }

    // --- output head (16 -> 1): tanh then f32 partial dot with SCALED wout;
    //     pa-pb is the pre-scaled final argument. Complement from lane^32.
    asm volatile("" ::: "memory");
    float pa = 0.0f, pb = 0.0f;
    #pragma unroll
    for (int p = 0; p < 8; ++p) {
        const float wo = sw[896 + SIG(g, p)];
        pa = fmaf(fast_tanh_pre(da[p]), wo, pa);
        pb = fmaf(fast_tanh_pre(db[p]), wo, pb);
    }
    pa += __shfl_xor(pa, 32);
    pb += __shfl_xor(pb, 32);

    const float tr  = fast_tanh_pre(pa - pb);   // arg pre-scaled via wout
    const float fac = (tr < 0.0f) ? o0 : n0;
    if (lane < 32)
        ws[k * NVOX + vox] = tr * fac * g_dinv[k];
}

// ---------------------------------------------------------------------------
// Pass 2: per voxel u, total = sum_k ( f[k][u] - f[k][u - d_k] ).
__global__ __launch_bounds__(256)
void gather_kernel(const float* __restrict__ q,
                   const float* __restrict__ ws,
                   float* __restrict__ out)
{
    const int vox = blockIdx.x * 256 + threadIdx.x;

    const int z = vox % NSIDE;
    const int y = (vox / NSIDE) % NSIDE;
    const int x = vox / (NSIDE * NSIDE);
    const int xm = (x == 0) ? NSIDE - 1 : x - 1;
    const int ym = (y == 0) ? NSIDE - 1 : y - 1;
    const int yp = (y == NSIDE - 1) ? 0 : y + 1;
    const int zm = (z == 0) ? NSIDE - 1 : z - 1;
    const int zp = (z == NSIDE - 1) ? 0 : z + 1;

    float s = 0.0f;
    #pragma unroll
    for (int k = 0; k < NDIR; ++k) {
        const int px = g_ox[k] ? xm : x;
        const int py = (g_oy[k] > 0) ? ym : ((g_oy[k] < 0) ? yp : y);
        const int pz = (g_oz[k] > 0) ? zm : ((g_oz[k] < 0) ? zp : z);
        s += ws[k * NVOX + vox];
        s -= ws[k * NVOX + (px * NSIDE + py) * NSIDE + pz];
    }

    const float2 own = reinterpret_cast<const float2*>(q)[vox];
    float2 r;
    r.x = fmaf(s, SCALE, own.x);
    r.y = own.y;
    reinterpret_cast<float2*>(out)[vox] = r;
}

// ---------------------------------------------------------------------------
// Fallback: Round-3 single-pass scalar kernel (used only if ws is too small).
#define LAYER(WB, INA, INB, OUTA, OUTB)                                        \
    {                                                                          \
        _Pragma("unroll")                                                      \
        for (int i = 0; i < 16; ++i) {                                         \
            float aa = sw[(WB) + 256 + i];                                     \
            float ab = aa;                                                     \
            _Pragma("unroll")                                                  \
            for (int kk = 0; kk < 4; ++kk) {                                   \
                const float4 w = *reinterpret_cast<const float4*>(             \
                    &sw[(WB) + i * 16 + kk * 4]);                              \
                aa = fmaf(w.x, INA[4 * kk + 0], aa);                           \
                aa = fmaf(w.y, INA[4 * kk + 1], aa);                           \
                aa = fmaf(w.z, INA[4 * kk + 2], aa);                           \
                aa = fmaf(w.w, INA[4 * kk + 3], aa);                           \
                ab = fmaf(w.x, INB[4 * kk + 0], ab);                           \
                ab = fmaf(w.y, INB[4 * kk + 1], ab);                           \
                ab = fmaf(w.z, INB[4 * kk + 2], ab);                           \
                ab = fmaf(w.w, INB[4 * kk + 3], ab);                           \
            }                                                                  \
            OUTA[i] = fast_tanh(aa);                                           \
            OUTB[i] = fast_tanh(ab);                                           \
        }                                                                      \
    }

__global__ __launch_bounds__(256)
void automaton_kernel(const float* __restrict__ q,
                      const float* __restrict__ W0, const float* __restrict__ b0,
                      const float* __restrict__ W1, const float* __restrict__ b1,
                      const float* __restrict__ W2, const float* __restrict__ b2,
                      const float* __restrict__ W3, const float* __restrict__ b3,
                      const float* __restrict__ Wout, const float* __restrict__ bout,
                      float* __restrict__ out)
{
    STAGE_WEIGHTS_256()

    const int gid  = blockIdx.x * 256 + threadIdx.x;
    const int vox  = gid >> 1;
    const int half = gid & 1;

    const int z = vox % NSIDE;
    const int y = (vox / NSIDE) % NSIDE;
    const int x = vox / (NSIDE * NSIDE);
    const int xm = (x == 0) ? NSIDE - 1 : x - 1;
    const int xp = (x == NSIDE - 1) ? 0 : x + 1;
    const int ym = (y == 0) ? NSIDE - 1 : y - 1;
    const int yp = (y == NSIDE - 1) ? 0 : y + 1;
    const int zm = (z == 0) ? NSIDE - 1 : z - 1;
    const int zp = (z == NSIDE - 1) ? 0 : z + 1;

    const float2 own = reinterpret_cast<const float2*>(q)[vox];
    const float o0 = own.x, o1 = own.y;

    float sum = 0.0f;
    #pragma unroll 1
    for (int k = half * 13; k < half * 13 + 13; ++k) {
        asm volatile("" ::: "memory");   // block cross-iteration LICM of weight loads
        const int ox = c_ox[k], oy = c_oy[k], oz = c_oz[k];
        const int nx = (ox < 0) ? xm : ((ox > 0) ? xp : x);
        const int ny = (oy < 0) ? ym : ((oy > 0) ? yp : y);
        const int nz = (oz < 0) ? zm : ((oz > 0) ? zp : z);
        const float2 nbq = reinterpret_cast<const float2*>(q)[(nx * NSIDE + ny) * NSIDE + nz];
        const float n0 = nbq.x, n1 = nbq.y;

        float ha[16], hb[16], ta[16], tb[16];
        #pragma unroll
        for (int i = 0; i < 16; ++i) {
            const float4 w = *reinterpret_cast<const float4*>(&sw[i * 4]);
            const float bbias = sw[64 + i];
            float pa = fmaf(w.x, o0, fmaf(w.y, o1, fmaf(w.z, n0, fmaf(w.w, n1, bbias))));
            float pb = fmaf(w.x, n0, fmaf(w.y, n1, fmaf(w.z, o0, fmaf(w.w, o1, bbias))));
            ha[i] = fast_tanh(pa);
            hb[i] = fast_tanh(pb);
        }
        LAYER(80,  ha, hb, ta, tb)
        LAYER(352, ta, tb, ha, hb)
        LAYER(624, ha, hb, ta, tb)
        float oa = sw[912], ob = sw[912];
        #pragma unroll
        for (int kk = 0; kk < 4; ++kk) {
            const float4 w = *reinterpret_cast<const float4*>(&sw[896 + kk * 4]);
            oa = fmaf(w.x, ta[4 * kk + 0], oa);
            oa = fmaf(w.y, ta[4 * kk + 1], oa);
            oa = fmaf(w.z, ta[4 * kk + 2], oa);
            oa = fmaf(w.w, ta[4 * kk + 3], oa);
            ob = fmaf(w.x, tb[4 * kk + 0], ob);
            ob = fmaf(w.y, tb[4 * kk + 1], ob);
            ob = fmaf(w.z, tb[4 * kk + 2], ob);
            ob = fmaf(w.w, tb[4 * kk + 3], ob);
        }
        const float tr  = fast_tanh(oa - ob);
        const float fac = (tr < 0.0f) ? o0 : n0;
        sum = fmaf(tr * fac, c_dinv[k], sum);
    }

    sum += __shfl_xor(sum, 1);
    if (half == 0) {
        float2 r;
        r.x = fmaf(sum, SCALE, o0);
        r.y = o1;
        reinterpret_cast<float2*>(out)[vox] = r;
    }
}

extern "C" void kernel_launch(void* const* d_in, const int* in_sizes, int n_in,
                              void* d_out, int out_size, void* d_ws, size_t ws_size,
                              hipStream_t stream) {
    const float* q    = (const float*)d_in[0];
    const float* W0   = (const float*)d_in[1];
    const float* b0   = (const float*)d_in[2];
    const float* W1   = (const float*)d_in[3];
    const float* b1   = (const float*)d_in[4];
    const float* W2   = (const float*)d_in[5];
    const float* b2   = (const float*)d_in[6];
    const float* W3   = (const float*)d_in[7];
    const float* b3   = (const float*)d_in[8];
    const float* Wout = (const float*)d_in[9];
    const float* bout = (const float*)d_in[10];
    float* out = (float*)d_out;

    const size_t ws_needed = (size_t)NDIR * NVOX * sizeof(float);  // 5.75 MB
    if (ws_size >= ws_needed) {
        float* ws = (float*)d_ws;
        flux_mfma_kernel<<<dim3(NDIR * BLOCKS_PER_DIR), dim3(256), 0, stream>>>(
            q, W0, b0, W1, b1, W2, b2, W3, b3, Wout, bout, ws);
        gather_kernel<<<dim3(NVOX / 256), dim3(256), 0, stream>>>(q, ws, out);
    } else {
        automaton_kernel<<<dim3(NVOX * 2 / 256), dim3(256), 0, stream>>>(
            q, W0, b0, W1, b1, W2, b2, W3, b3, Wout, bout, out);
    }
}